// Round 3
// baseline (9432.018 us; speedup 1.0000x reference)
//
#include <hip/hip_runtime.h>
#include <math.h>

// Residual VQ matching a float32 numpy reference:
//   scores = x2 + e2 - 2*(res @ emb.T)  computed/rounded in f32, argmin=first-min.
// Key: the final f32 rounding at |score|~x2~128 (ulp ~7.6e-6) determines
// near-tie winners. We replicate: e2/x2 in numpy pairwise-sum order with
// f32-rounded squares, A=fl32(x2+e2k), S=fl32(A-2*fl32(dot_exact)), first-min.
// Hot path stays fast-fp32 with a 4e-4 top-2 margin; flagged rows (~1e-4 rate)
// do the full replicated rescan. Residual update r-=q in plain f32 (bit-exact).

#define D_DIM 128
#define K_CB  1024
#define L_LVL 4
#define NJ    (D_DIM / 4)

// force f32 rounding of a product (blocks fma contraction under -ffp-contract=fast)
static __device__ __forceinline__ float mulr(float a, float b) {
    float p = a * b;
    asm volatile("" : "+v"(p));
    return p;
}

static __device__ __forceinline__ float f4c(const float4& v, int c) {
    switch (c & 3) { case 0: return v.x; case 1: return v.y; case 2: return v.z; default: return v.w; }
}

__global__ __launch_bounds__(256, 2)
void rvq_kernel(const float* __restrict__ residual,
                const float* __restrict__ codebooks,
                float* __restrict__ out, int B) {
    __shared__ float e2s[L_LVL * K_CB];  // ||e||^2, numpy-pairwise f32 exact

    // per-block e2 table: numpy pairwise order (8 stride-8 accs, then tree)
    for (int i = threadIdx.x; i < L_LVL * K_CB; i += blockDim.x) {
        const float* e = codebooks + (size_t)i * D_DIM;
        float r8[8];
        #pragma unroll
        for (int j = 0; j < 8; ++j) r8[j] = mulr(e[j], e[j]);
        #pragma unroll
        for (int b = 1; b < 16; ++b)
            #pragma unroll
            for (int j = 0; j < 8; ++j) r8[j] += mulr(e[b * 8 + j], e[b * 8 + j]);
        e2s[i] = ((r8[0] + r8[1]) + (r8[2] + r8[3])) + ((r8[4] + r8[5]) + (r8[6] + r8[7]));
    }
    __syncthreads();

    int row = blockIdx.x * blockDim.x + threadIdx.x;
    if (row >= B) return;

    const float4* rp = (const float4*)(residual + (size_t)row * D_DIM);
    float4 rr[NJ];
    #pragma unroll
    for (int j = 0; j < NJ; ++j) rr[j] = rp[j];

    float codes_f[L_LVL];

    for (int l = 0; l < L_LVL; ++l) {
        const float* cbl = codebooks + (size_t)l * K_CB * D_DIM;
        const float* e2l = &e2s[l * K_CB];

        float best = 3.4e38f, best2 = 3.4e38f;
        int bidx = 0;

        // ---- fast fp32 scoring (x2 omitted: constant per row) ----
        for (int k = 0; k < K_CB; ++k) {
            const float4* ek = (const float4*)(cbl + (size_t)k * D_DIM);
            float p0 = 0.f, p1 = 0.f, p2 = 0.f, p3 = 0.f;
            #pragma unroll
            for (int j = 0; j < NJ; ++j) {
                float4 v = ek[j];
                p0 = fmaf(rr[j].x, v.x, p0);
                p1 = fmaf(rr[j].y, v.y, p1);
                p2 = fmaf(rr[j].z, v.z, p2);
                p3 = fmaf(rr[j].w, v.w, p3);
            }
            float sc = fmaf(-2.0f, (p0 + p1) + (p2 + p3), e2l[k]);
            if (sc < best)       { best2 = best; best = sc; bidx = k; }
            else if (sc < best2) { best2 = sc; }
        }

        // ---- ambiguous: full rescan replicating the reference's f32 scores ----
        const float MARGIN = 4e-4f;  // ~4.5x combined (hot-err + S-reconstruction) bound
        if (best2 - best <= MARGIN) {
            // x2 = numpy pairwise f32 sum of fl32(r_i^2); elem i=j+8b -> rr[(j>>2)+2b].comp(j&3)
            float r8[8];
            #pragma unroll
            for (int j = 0; j < 8; ++j) {
                float v0 = f4c(rr[j >> 2], j);
                float acc = mulr(v0, v0);
                #pragma unroll
                for (int b = 1; b < 16; ++b) {
                    float v = f4c(rr[(j >> 2) + 2 * b], j);
                    acc += mulr(v, v);
                }
                r8[j] = acc;
            }
            float x2 = ((r8[0] + r8[1]) + (r8[2] + r8[3])) + ((r8[4] + r8[5]) + (r8[6] + r8[7]));

            float bestS = 3.4e38f;
            int bi = 0;
            for (int k = 0; k < K_CB; ++k) {
                const float4* ek = (const float4*)(cbl + (size_t)k * D_DIM);
                double dd = 0.0;
                #pragma unroll
                for (int j = 0; j < NJ; ++j) {
                    float4 v = ek[j];
                    dd = fma((double)v.x, (double)rr[j].x, dd);
                    dd = fma((double)v.y, (double)rr[j].y, dd);
                    dd = fma((double)v.z, (double)rr[j].z, dd);
                    dd = fma((double)v.w, (double)rr[j].w, dd);
                }
                float M = (float)dd;            // fl32(exact dot), ~BLAS to 1-2 ulp
                float A = x2 + e2l[k];          // fl32(x2 + e2_k), ulp(~129)
                float S = A - 2.0f * M;         // final rounding at |score|~128
                if (S < bestS) { bestS = S; bi = k; }  // strict <: first-min
            }
            bidx = bi;
        }
        codes_f[l] = (float)bidx;

        // ---- residual update: plain f32 r -= q (bit-exact vs reference) ----
        const float4* q = (const float4*)(cbl + (size_t)bidx * D_DIM);
        #pragma unroll
        for (int j = 0; j < NJ; ++j) {
            float4 v = q[j];
            rr[j].x -= v.x; rr[j].y -= v.y; rr[j].z -= v.z; rr[j].w -= v.w;
        }
    }

    // quantized = r0 - r_final (within ~1e-6 of ref's q0+q1+q2+q3; thr 20.48)
    float4* op = (float4*)(out + (size_t)row * D_DIM);
    #pragma unroll
    for (int j = 0; j < NJ; ++j) {
        float4 r0 = rp[j];
        float4 o;
        o.x = r0.x - rr[j].x; o.y = r0.y - rr[j].y;
        o.z = r0.z - rr[j].z; o.w = r0.w - rr[j].w;
        op[j] = o;
    }

    float4* cp = (float4*)(out + (size_t)B * D_DIM + (size_t)row * L_LVL);
    *cp = make_float4(codes_f[0], codes_f[1], codes_f[2], codes_f[3]);
}

extern "C" void kernel_launch(void* const* d_in, const int* in_sizes, int n_in,
                              void* d_out, int out_size, void* d_ws, size_t ws_size,
                              hipStream_t stream) {
    const float* residual  = (const float*)d_in[0];
    const float* codebooks = (const float*)d_in[1];
    float* out = (float*)d_out;
    int B = in_sizes[0] / D_DIM;  // 131072
    dim3 grid((B + 255) / 256), block(256);
    hipLaunchKernelGGL(rvq_kernel, grid, block, 0, stream,
                       residual, codebooks, out, B);
}